// Round 5
// baseline (593.670 us; speedup 1.0000x reference)
//
#include <hip/hip_runtime.h>

// GAT layer collapse: softmax over a row-constant score == uniform over neighbors.
// h_prime[i] = (sum_{j: adj[i][j]>0} Wh[j]) / deg(i),  Wh = h @ W.
// a1/a2/LeakyReLU are mathematically irrelevant (softmax shift invariance +
// exp(NEG_BIG) fp32 underflow to 0).
//
// R5: R2 and R4 failed with IDENTICAL absmax; their only shared novelty was
// the int4-packed + bit_cast afrag build -> quarantined. This round keeps the
// R4 idea (BW-saturating adj->bitmask kernel; MFMA kernel reads 12.8 MB mask)
// but: mask packed per-lane with explicit shifts (no ballot, no bit_cast),
// gat_agg is R1's proven code with afrag[t] element-wise from mask bits.

#define N_NODES 10000
#define KPAD    10016          // 313*32, padded K for MFMA steps
#define NSTEP   313            // ceil(10000/32)
#define OUTF    64
#define MROWB   1280           // mask row stride bytes (320 u32 words)

typedef __attribute__((ext_vector_type(8))) short short8;   // 8 bf16 (4 VGPRs)
typedef __attribute__((ext_vector_type(4))) float f32x4;    // 4 fp32 acc

__device__ __forceinline__ unsigned short f2bf(float x) {
    unsigned int u = __builtin_bit_cast(unsigned int, x);
    u = (u + 0x7FFFu + ((u >> 16) & 1u)) >> 16;   // RNE
    return (unsigned short)u;
}

// Kernel 1 (R3, proven): Wh = h @ W (fp32), bf16 packed as
// Bpack[((k>>3)*64 + n)*8 + (k&7)]; block 0 zero-fills pad rows 10000..10015.
__global__ __launch_bounds__(256) void wh_pack_kernel(
    const float* __restrict__ h, const float* __restrict__ W,
    unsigned short* __restrict__ Bpack) {
    __shared__ float Wl[128 * 64];   // 32 KB
    __shared__ float Hl[16 * 128];   // 8 KB
    const int tid = threadIdx.x;
    const int i0  = blockIdx.x * 16;             // 625 * 16 = 10000 exact
    const float4* W4 = (const float4*)W;
    float4* Wl4 = (float4*)Wl;
    #pragma unroll
    for (int t = 0; t < 8; ++t) Wl4[t * 256 + tid] = W4[t * 256 + tid];
    const float4* H4 = (const float4*)(h + (size_t)i0 * 128);
    float4* Hl4 = (float4*)Hl;
    #pragma unroll
    for (int t = 0; t < 2; ++t) Hl4[t * 256 + tid] = H4[t * 256 + tid];
    if (blockIdx.x == 0) {
        #pragma unroll
        for (int t = 0; t < 4; ++t)
            Bpack[(size_t)N_NODES * OUTF + tid * 4 + t] = 0;
    }
    __syncthreads();
    const int n  = tid & 63;
    const int rq = tid >> 6;
    float acc0 = 0.f, acc1 = 0.f, acc2 = 0.f, acc3 = 0.f;
    #pragma unroll 8
    for (int j = 0; j < 128; ++j) {
        const float w = Wl[j * 64 + n];
        acc0 += Hl[(rq * 4 + 0) * 128 + j] * w;
        acc1 += Hl[(rq * 4 + 1) * 128 + j] * w;
        acc2 += Hl[(rq * 4 + 2) * 128 + j] * w;
        acc3 += Hl[(rq * 4 + 3) * 128 + j] * w;
    }
    const float accs[4] = {acc0, acc1, acc2, acc3};
    #pragma unroll
    for (int t = 0; t < 4; ++t) {
        const int i = i0 + rq * 4 + t;
        Bpack[((size_t)(i >> 3) * 64 + n) * 8 + (i & 7)] = f2bf(accs[t]);
    }
}

// Kernel 2 (NEW, no cross-lane ops): pack adj row -> 1-bit mask.
// One block per row; thread w packs u32 word w: bit b = (adj[row][w*32+b] != 0).
// 8 independent int4 loads in flight per word; fully streaming 400 MB read.
__global__ __launch_bounds__(256) void mask_pack_kernel(
    const int* __restrict__ adj, unsigned int* __restrict__ mask) {
    const int row = blockIdx.x;
    const int tid = threadIdx.x;
    const int4* __restrict__ arow4 = (const int4*)(adj + (size_t)row * N_NODES);
    unsigned int* __restrict__ mrow = mask + (size_t)row * (MROWB / 4);
    for (int w = tid; w < MROWB / 4; w += 256) {
        unsigned int word = 0u;
        if (w < 312) {                             // cols w*32 .. w*32+31, in-bounds
            #pragma unroll
            for (int j = 0; j < 8; ++j) {
                const int4 v = arow4[w * 8 + j];
                word |= (v.x != 0 ? 1u : 0u) << (j * 4 + 0);
                word |= (v.y != 0 ? 1u : 0u) << (j * 4 + 1);
                word |= (v.z != 0 ? 1u : 0u) << (j * 4 + 2);
                word |= (v.w != 0 ? 1u : 0u) << (j * 4 + 3);
            }
        } else if (w == 312) {                     // cols 9984..9999 only
            #pragma unroll
            for (int j = 0; j < 4; ++j) {
                const int4 v = arow4[w * 8 + j];
                word |= (v.x != 0 ? 1u : 0u) << (j * 4 + 0);
                word |= (v.y != 0 ? 1u : 0u) << (j * 4 + 1);
                word |= (v.z != 0 ? 1u : 0u) << (j * 4 + 2);
                word |= (v.w != 0 ? 1u : 0u) << (j * 4 + 3);
            }
        }                                          // w 313..319: zero pad
        mrow[w] = word;
    }
}

// Kernel 3 (R1 structure verbatim; only the afrag SOURCE changed to mask bits).
// Grid = 625*S blocks, 4 waves. Block (tile,q): rows [tile*16,+16),
// K-steps s = q*4+wave, stride 4S. afrag[t] element-wise (R1's proven form).
__global__ __launch_bounds__(256) void gat_agg_kernel(
    const unsigned int* __restrict__ mask, const unsigned short* __restrict__ Bpack,
    float* __restrict__ Cpart, int* __restrict__ degpart, int S) {
    const int bx   = blockIdx.x;
    const int tile = bx / S;
    const int q    = bx - tile * S;
    const int tidx = threadIdx.x;
    const int wave = tidx >> 6;
    const int lane = tidx & 63;
    const int r16  = lane & 15;
    const int quad = lane >> 4;
    const int row  = tile * 16 + r16;
    const unsigned int* __restrict__ mrow = mask + (size_t)row * (MROWB / 4);
    const short8* __restrict__ bbase = (const short8*)Bpack;

    f32x4 acc[4];
    #pragma unroll
    for (int c = 0; c < 4; ++c) acc[c] = (f32x4){0.f, 0.f, 0.f, 0.f};
    int msum = 0;

    const int slot = q * 4 + wave;
    const int stride = S * 4;
    for (int s = slot; s < NSTEP; s += stride) {
        const unsigned int m   = mrow[s];          // bits = cols s*32 .. s*32+31
        const unsigned int myb = (m >> (quad * 8)) & 0xFFu;   // this quad's 8 cols
        short8 afrag;
        #pragma unroll
        for (int t = 0; t < 8; ++t)
            afrag[t] = ((myb >> t) & 1u) ? (short)0x3F80 : (short)0;
        msum += (int)__popc(myb);
        const int g = s * 4 + quad;                // k-group index into Bpack
        const short8* __restrict__ bg = bbase + (size_t)g * 64 + r16;
        const short8 b0 = bg[0];
        const short8 b1 = bg[16];
        const short8 b2 = bg[32];
        const short8 b3 = bg[48];
        acc[0] = __builtin_amdgcn_mfma_f32_16x16x32_bf16(afrag, b0, acc[0], 0, 0, 0);
        acc[1] = __builtin_amdgcn_mfma_f32_16x16x32_bf16(afrag, b1, acc[1], 0, 0, 0);
        acc[2] = __builtin_amdgcn_mfma_f32_16x16x32_bf16(afrag, b2, acc[2], 0, 0, 0);
        acc[3] = __builtin_amdgcn_mfma_f32_16x16x32_bf16(afrag, b3, acc[3], 0, 0, 0);
    }

    // deg: fold quads (lanes L, L+16, L+32, L+48 share row r16)
    msum += __shfl_down(msum, 32);
    msum += __shfl_down(msum, 16);

    __shared__ float Cred[4][16][64];
    __shared__ int   degred[4][16];
    #pragma unroll
    for (int c = 0; c < 4; ++c) {
        #pragma unroll
        for (int r = 0; r < 4; ++r)
            Cred[wave][quad * 4 + r][c * 16 + r16] = acc[c][r];
    }
    if (lane < 16) degred[wave][lane] = msum;
    __syncthreads();

    for (int e = tidx; e < 16 * 64; e += 256) {
        const int r = e >> 6, n = e & 63;
        const float sum = Cred[0][r][n] + Cred[1][r][n] + Cred[2][r][n] + Cred[3][r][n];
        Cpart[((size_t)q * N_NODES + tile * 16 + r) * 64 + n] = sum;
    }
    if (tidx < 16)
        degpart[q * N_NODES + tile * 16 + tidx] =
            degred[0][tidx] + degred[1][tidx] + degred[2][tidx] + degred[3][tidx];
}

// Kernel 4 (R1 verbatim): out[i][n] = (sum_q Cpart[q][i][n]) / deg[i]
__global__ __launch_bounds__(256) void finalize_kernel(
    const float* __restrict__ Cpart, const int* __restrict__ degpart,
    float* __restrict__ out, int S) {
    const int idx = blockIdx.x * 256 + threadIdx.x;
    if (idx >= N_NODES * OUTF) return;
    const int i = idx >> 6;
    float sum = 0.f;
    int deg = 0;
    for (int qq = 0; qq < S; ++qq) {
        sum += Cpart[(size_t)qq * N_NODES * OUTF + idx];
        deg += degpart[qq * N_NODES + i];
    }
    out[idx] = (deg > 0) ? sum / (float)deg : 0.f;
}

extern "C" void kernel_launch(void* const* d_in, const int* in_sizes, int n_in,
                              void* d_out, int out_size, void* d_ws, size_t ws_size,
                              hipStream_t stream) {
    const float* h   = (const float*)d_in[0];
    const int*   adj = (const int*)d_in[1];
    const float* W   = (const float*)d_in[2];
    // d_in[3] (a1) and d_in[4] (a2) are mathematically irrelevant (see header).
    float* out = (float*)d_out;
    char*  ws  = (char*)d_ws;
    const int S = 8;

    size_t off = 0;
    unsigned short* Bpack = (unsigned short*)(ws + off);
    off += ((size_t)KPAD * OUTF * 2 + 255) & ~(size_t)255;           // 1.28 MB
    unsigned int* mask = (unsigned int*)(ws + off);
    off += ((size_t)N_NODES * MROWB + 255) & ~(size_t)255;           // 12.8 MB
    int* degpart = (int*)(ws + off);
    off += ((size_t)S * N_NODES * 4 + 255) & ~(size_t)255;           // 320 KB
    float* Cpart = (float*)(ws + off);                               // 20.48 MB

    wh_pack_kernel<<<dim3(625), dim3(256), 0, stream>>>(h, W, Bpack);
    mask_pack_kernel<<<dim3(N_NODES), dim3(256), 0, stream>>>(adj, mask);
    gat_agg_kernel<<<dim3(625 * S), dim3(256), 0, stream>>>(mask, Bpack, Cpart, degpart, S);
    finalize_kernel<<<dim3((N_NODES * OUTF + 255) / 256), dim3(256), 0, stream>>>(
        Cpart, degpart, out, S);
}

// Round 6
// 581.698 us; speedup vs baseline: 1.0206x; 1.0206x over previous
//
#include <hip/hip_runtime.h>

// GAT layer collapse: softmax over a row-constant score == uniform over neighbors.
// h_prime[i] = (sum_{j: adj[i][j]>0} Wh[j]) / deg(i),  Wh = h @ W.
// a1/a2/LeakyReLU are mathematically irrelevant (softmax shift invariance +
// exp(NEG_BIG) fp32 underflow to 0).
//
// R6: R5 showed the 400 MB adj read runs at ~2 TB/s because mask_pack's
// per-thread-contiguous-128B pattern issues 64 cache-line transactions per
// wave instruction. Fix: lane-coalesced int4 loads + LDS nibble staging.
// wh_pack / gat_agg / finalize are R5-verbatim (proven).

#define N_NODES 10000
#define KPAD    10016          // 313*32, padded K for MFMA steps
#define NSTEP   313            // ceil(10000/32)
#define OUTF    64
#define MROWB   1280           // mask row stride bytes (320 u32 words)

typedef __attribute__((ext_vector_type(8))) short short8;   // 8 bf16 (4 VGPRs)
typedef __attribute__((ext_vector_type(4))) float f32x4;    // 4 fp32 acc

__device__ __forceinline__ unsigned short f2bf(float x) {
    unsigned int u = __builtin_bit_cast(unsigned int, x);
    u = (u + 0x7FFFu + ((u >> 16) & 1u)) >> 16;   // RNE
    return (unsigned short)u;
}

// Kernel 1 (R3/R5, proven): Wh = h @ W (fp32), bf16 packed as
// Bpack[((k>>3)*64 + n)*8 + (k&7)]; block 0 zero-fills pad rows 10000..10015.
__global__ __launch_bounds__(256) void wh_pack_kernel(
    const float* __restrict__ h, const float* __restrict__ W,
    unsigned short* __restrict__ Bpack) {
    __shared__ float Wl[128 * 64];   // 32 KB
    __shared__ float Hl[16 * 128];   // 8 KB
    const int tid = threadIdx.x;
    const int i0  = blockIdx.x * 16;             // 625 * 16 = 10000 exact
    const float4* W4 = (const float4*)W;
    float4* Wl4 = (float4*)Wl;
    #pragma unroll
    for (int t = 0; t < 8; ++t) Wl4[t * 256 + tid] = W4[t * 256 + tid];
    const float4* H4 = (const float4*)(h + (size_t)i0 * 128);
    float4* Hl4 = (float4*)Hl;
    #pragma unroll
    for (int t = 0; t < 2; ++t) Hl4[t * 256 + tid] = H4[t * 256 + tid];
    if (blockIdx.x == 0) {
        #pragma unroll
        for (int t = 0; t < 4; ++t)
            Bpack[(size_t)N_NODES * OUTF + tid * 4 + t] = 0;
    }
    __syncthreads();
    const int n  = tid & 63;
    const int rq = tid >> 6;
    float acc0 = 0.f, acc1 = 0.f, acc2 = 0.f, acc3 = 0.f;
    #pragma unroll 8
    for (int j = 0; j < 128; ++j) {
        const float w = Wl[j * 64 + n];
        acc0 += Hl[(rq * 4 + 0) * 128 + j] * w;
        acc1 += Hl[(rq * 4 + 1) * 128 + j] * w;
        acc2 += Hl[(rq * 4 + 2) * 128 + j] * w;
        acc3 += Hl[(rq * 4 + 3) * 128 + j] * w;
    }
    const float accs[4] = {acc0, acc1, acc2, acc3};
    #pragma unroll
    for (int t = 0; t < 4; ++t) {
        const int i = i0 + rq * 4 + t;
        Bpack[((size_t)(i >> 3) * 64 + n) * 8 + (i & 7)] = f2bf(accs[t]);
    }
}

// Kernel 2 (REWRITTEN): pack adj row -> 1-bit mask, lane-coalesced.
// One block per row. Phase 1: thread reads arow4[tid + 256k] (adjacent lanes
// -> adjacent 16B), stores 4-bit nibble (cols idx*4..idx*4+3) to LDS.
// Phase 2: thread w assembles word w from 8 nibbles (explicit shifts).
// Bit b of word w = (adj[row][w*32+b] != 0) — same format R5's gat_agg proved.
__global__ __launch_bounds__(256) void mask_pack_kernel(
    const int* __restrict__ adj, unsigned int* __restrict__ mask) {
    __shared__ unsigned char nib[2560];          // 2500 used + zero pad
    const int row = blockIdx.x;
    const int tid = threadIdx.x;
    const int4* __restrict__ arow4 = (const int4*)(adj + (size_t)row * N_NODES);
    if (tid < 60) nib[2500 + tid] = 0;           // pad nibbles -> 0
    // 2500 int4s per row; unroll 4 => 4 independent coalesced loads in flight
    for (int base = 0; base < 2500; base += 1024) {
        int4 v[4];
        #pragma unroll
        for (int k = 0; k < 4; ++k) {
            const int idx = base + k * 256 + tid;
            v[k] = (idx < 2500) ? arow4[idx] : (int4){0, 0, 0, 0};
        }
        #pragma unroll
        for (int k = 0; k < 4; ++k) {
            const int idx = base + k * 256 + tid;
            const unsigned int b = (v[k].x != 0 ? 1u : 0u) | (v[k].y != 0 ? 2u : 0u)
                                 | (v[k].z != 0 ? 4u : 0u) | (v[k].w != 0 ? 8u : 0u);
            if (idx < 2500) nib[idx] = (unsigned char)b;
        }
    }
    __syncthreads();
    unsigned int* __restrict__ mrow = mask + (size_t)row * (MROWB / 4);
    for (int w = tid; w < MROWB / 4; w += 256) {
        unsigned int word = 0u;
        if (w < 313) {                           // w==312 pads via zeroed nibbles
            #pragma unroll
            for (int j = 0; j < 8; ++j)
                word |= (unsigned int)nib[w * 8 + j] << (j * 4);
        }
        mrow[w] = word;
    }
}

// Kernel 3 (R5 verbatim, proven): masked aggregation via MFMA from mask bits.
// Grid = 625*S blocks, 4 waves. Block (tile,q): rows [tile*16,+16),
// K-steps s = q*4+wave, stride 4S. afrag[t] element-wise (R1's proven form).
__global__ __launch_bounds__(256) void gat_agg_kernel(
    const unsigned int* __restrict__ mask, const unsigned short* __restrict__ Bpack,
    float* __restrict__ Cpart, int* __restrict__ degpart, int S) {
    const int bx   = blockIdx.x;
    const int tile = bx / S;
    const int q    = bx - tile * S;
    const int tidx = threadIdx.x;
    const int wave = tidx >> 6;
    const int lane = tidx & 63;
    const int r16  = lane & 15;
    const int quad = lane >> 4;
    const int row  = tile * 16 + r16;
    const unsigned int* __restrict__ mrow = mask + (size_t)row * (MROWB / 4);
    const short8* __restrict__ bbase = (const short8*)Bpack;

    f32x4 acc[4];
    #pragma unroll
    for (int c = 0; c < 4; ++c) acc[c] = (f32x4){0.f, 0.f, 0.f, 0.f};
    int msum = 0;

    const int slot = q * 4 + wave;
    const int stride = S * 4;
    for (int s = slot; s < NSTEP; s += stride) {
        const unsigned int m   = mrow[s];          // bits = cols s*32 .. s*32+31
        const unsigned int myb = (m >> (quad * 8)) & 0xFFu;   // this quad's 8 cols
        short8 afrag;
        #pragma unroll
        for (int t = 0; t < 8; ++t)
            afrag[t] = ((myb >> t) & 1u) ? (short)0x3F80 : (short)0;
        msum += (int)__popc(myb);
        const int g = s * 4 + quad;                // k-group index into Bpack
        const short8* __restrict__ bg = bbase + (size_t)g * 64 + r16;
        const short8 b0 = bg[0];
        const short8 b1 = bg[16];
        const short8 b2 = bg[32];
        const short8 b3 = bg[48];
        acc[0] = __builtin_amdgcn_mfma_f32_16x16x32_bf16(afrag, b0, acc[0], 0, 0, 0);
        acc[1] = __builtin_amdgcn_mfma_f32_16x16x32_bf16(afrag, b1, acc[1], 0, 0, 0);
        acc[2] = __builtin_amdgcn_mfma_f32_16x16x32_bf16(afrag, b2, acc[2], 0, 0, 0);
        acc[3] = __builtin_amdgcn_mfma_f32_16x16x32_bf16(afrag, b3, acc[3], 0, 0, 0);
    }

    // deg: fold quads (lanes L, L+16, L+32, L+48 share row r16)
    msum += __shfl_down(msum, 32);
    msum += __shfl_down(msum, 16);

    __shared__ float Cred[4][16][64];
    __shared__ int   degred[4][16];
    #pragma unroll
    for (int c = 0; c < 4; ++c) {
        #pragma unroll
        for (int r = 0; r < 4; ++r)
            Cred[wave][quad * 4 + r][c * 16 + r16] = acc[c][r];
    }
    if (lane < 16) degred[wave][lane] = msum;
    __syncthreads();

    for (int e = tidx; e < 16 * 64; e += 256) {
        const int r = e >> 6, n = e & 63;
        const float sum = Cred[0][r][n] + Cred[1][r][n] + Cred[2][r][n] + Cred[3][r][n];
        Cpart[((size_t)q * N_NODES + tile * 16 + r) * 64 + n] = sum;
    }
    if (tidx < 16)
        degpart[q * N_NODES + tile * 16 + tidx] =
            degred[0][tidx] + degred[1][tidx] + degred[2][tidx] + degred[3][tidx];
}

// Kernel 4 (R1 verbatim, proven): out[i][n] = (sum_q Cpart[q][i][n]) / deg[i]
__global__ __launch_bounds__(256) void finalize_kernel(
    const float* __restrict__ Cpart, const int* __restrict__ degpart,
    float* __restrict__ out, int S) {
    const int idx = blockIdx.x * 256 + threadIdx.x;
    if (idx >= N_NODES * OUTF) return;
    const int i = idx >> 6;
    float sum = 0.f;
    int deg = 0;
    for (int qq = 0; qq < S; ++qq) {
        sum += Cpart[(size_t)qq * N_NODES * OUTF + idx];
        deg += degpart[qq * N_NODES + i];
    }
    out[idx] = (deg > 0) ? sum / (float)deg : 0.f;
}

extern "C" void kernel_launch(void* const* d_in, const int* in_sizes, int n_in,
                              void* d_out, int out_size, void* d_ws, size_t ws_size,
                              hipStream_t stream) {
    const float* h   = (const float*)d_in[0];
    const int*   adj = (const int*)d_in[1];
    const float* W   = (const float*)d_in[2];
    // d_in[3] (a1) and d_in[4] (a2) are mathematically irrelevant (see header).
    float* out = (float*)d_out;
    char*  ws  = (char*)d_ws;
    const int S = 8;

    size_t off = 0;
    unsigned short* Bpack = (unsigned short*)(ws + off);
    off += ((size_t)KPAD * OUTF * 2 + 255) & ~(size_t)255;           // 1.28 MB
    unsigned int* mask = (unsigned int*)(ws + off);
    off += ((size_t)N_NODES * MROWB + 255) & ~(size_t)255;           // 12.8 MB
    int* degpart = (int*)(ws + off);
    off += ((size_t)S * N_NODES * 4 + 255) & ~(size_t)255;           // 320 KB
    float* Cpart = (float*)(ws + off);                               // 20.48 MB

    wh_pack_kernel<<<dim3(625), dim3(256), 0, stream>>>(h, W, Bpack);
    mask_pack_kernel<<<dim3(N_NODES), dim3(256), 0, stream>>>(adj, mask);
    gat_agg_kernel<<<dim3(625 * S), dim3(256), 0, stream>>>(mask, Bpack, Cpart, degpart, S);
    finalize_kernel<<<dim3((N_NODES * OUTF + 255) / 256), dim3(256), 0, stream>>>(
        Cpart, degpart, out, S);
}

// Round 8
// 565.172 us; speedup vs baseline: 1.0504x; 1.0292x over previous
//
#include <hip/hip_runtime.h>

// GAT layer collapse: softmax over a row-constant score == uniform over neighbors.
// h_prime[i] = (sum_{j: adj[i][j]>0} Wh[j]) / deg(i),  Wh = h @ W.
// a1/a2/LeakyReLU are mathematically irrelevant (softmax shift invariance +
// exp(NEG_BIG) fp32 underflow to 0).
//
// R8: R2/R4/R7 all failed with IDENTICAL wrong output; the only shared factor
// across failures (and absent from all 4 passes) is a COMPILE-TIME K-loop
// stride / split constant in gat_agg+finalize. Rule: S stays a runtime kernel
// argument everywhere. This round = R3's proven gat_agg text + minimal
// depth-1 rotation prefetch of the adj pair (runtime stride preserved).

#define N_NODES 10000
#define KPAD    10016          // 313*32, padded K for MFMA steps
#define NSTEP   313            // ceil(10000/32)
#define OUTF    64

typedef __attribute__((ext_vector_type(8))) short short8;   // 8 bf16 (4 VGPRs)
typedef __attribute__((ext_vector_type(4))) float f32x4;    // 4 fp32 acc

__device__ __forceinline__ unsigned short f2bf(float x) {
    unsigned int u = __builtin_bit_cast(unsigned int, x);
    u = (u + 0x7FFFu + ((u >> 16) & 1u)) >> 16;   // RNE
    return (unsigned short)u;
}

// Kernel 1 (R3, proven): Wh = h @ W (fp32), bf16 packed as
// Bpack[((k>>3)*64 + n)*8 + (k&7)]; block 0 zero-fills pad rows 10000..10015.
__global__ __launch_bounds__(256) void wh_pack_kernel(
    const float* __restrict__ h, const float* __restrict__ W,
    unsigned short* __restrict__ Bpack) {
    __shared__ float Wl[128 * 64];   // 32 KB
    __shared__ float Hl[16 * 128];   // 8 KB
    const int tid = threadIdx.x;
    const int i0  = blockIdx.x * 16;             // 625 * 16 = 10000 exact
    const float4* W4 = (const float4*)W;
    float4* Wl4 = (float4*)Wl;
    #pragma unroll
    for (int t = 0; t < 8; ++t) Wl4[t * 256 + tid] = W4[t * 256 + tid];
    const float4* H4 = (const float4*)(h + (size_t)i0 * 128);
    float4* Hl4 = (float4*)Hl;
    #pragma unroll
    for (int t = 0; t < 2; ++t) Hl4[t * 256 + tid] = H4[t * 256 + tid];
    if (blockIdx.x == 0) {
        #pragma unroll
        for (int t = 0; t < 4; ++t)
            Bpack[(size_t)N_NODES * OUTF + tid * 4 + t] = 0;
    }
    __syncthreads();
    const int n  = tid & 63;
    const int rq = tid >> 6;
    float acc0 = 0.f, acc1 = 0.f, acc2 = 0.f, acc3 = 0.f;
    #pragma unroll 8
    for (int j = 0; j < 128; ++j) {
        const float w = Wl[j * 64 + n];
        acc0 += Hl[(rq * 4 + 0) * 128 + j] * w;
        acc1 += Hl[(rq * 4 + 1) * 128 + j] * w;
        acc2 += Hl[(rq * 4 + 2) * 128 + j] * w;
        acc3 += Hl[(rq * 4 + 3) * 128 + j] * w;
    }
    const float accs[4] = {acc0, acc1, acc2, acc3};
    #pragma unroll
    for (int t = 0; t < 4; ++t) {
        const int i = i0 + rq * 4 + t;
        Bpack[((size_t)(i >> 3) * 64 + n) * 8 + (i & 7)] = f2bf(accs[t]);
    }
}

// Kernel 2 (R3 text + depth-1 prefetch; S stays a RUNTIME argument).
// Grid = 625*S blocks, 4 waves. Block (tile,q): rows [tile*16,+16),
// K-steps s = q*4+wave, stride 4S.
__global__ __launch_bounds__(256) void gat_agg_kernel(
    const int* __restrict__ adj, const unsigned short* __restrict__ Bpack,
    float* __restrict__ Cpart, int* __restrict__ degpart, int S) {
    const int bx   = blockIdx.x;
    const int tile = bx / S;
    const int q    = bx - tile * S;
    const int tidx = threadIdx.x;
    const int wave = tidx >> 6;
    const int lane = tidx & 63;
    const int r16  = lane & 15;
    const int quad = lane >> 4;
    const int row  = tile * 16 + r16;
    const int* __restrict__ arow = adj + (size_t)row * N_NODES;
    const short8* __restrict__ bbase = (const short8*)Bpack;

    f32x4 acc[4];
    #pragma unroll
    for (int c = 0; c < 4; ++c) acc[c] = (f32x4){0.f, 0.f, 0.f, 0.f};
    int msum = 0;

    const int slot = q * 4 + wave;               // <= 31, so first step is main-branch
    const int stride = S * 4;

    // rotation registers: current step's adj pair (valid whenever the current
    // step takes the main branch, i.e. s < 312; tail does its own scalar loads)
    int4 c0v = *(const int4*)(arow + slot * 32 + quad * 8);
    int4 c1v = *(const int4*)(arow + slot * 32 + quad * 8 + 4);

    for (int s = slot; s < NSTEP; s += stride) {
        const int snext = s + stride;
        int4 n0 = {0, 0, 0, 0}, n1 = {0, 0, 0, 0};
        if (snext < 312) {                       // prefetch only main-branch steps
            n0 = *(const int4*)(arow + snext * 32 + quad * 8);
            n1 = *(const int4*)(arow + snext * 32 + quad * 8 + 4);
        }
        const int k0 = s * 32;
        const int kq = k0 + quad * 8;
        short8 afrag;
        if (k0 + 32 <= N_NODES) {                // main branch: use rotated pair
            const int vs[8] = {c0v.x, c0v.y, c0v.z, c0v.w, c1v.x, c1v.y, c1v.z, c1v.w};
            #pragma unroll
            for (int t = 0; t < 8; ++t) {
                const int m = vs[t] > 0;
                afrag[t] = m ? (short)0x3F80 : (short)0;
                msum += m;
            }
        } else {                                 // tail (s == 312): R3's guarded loads
            #pragma unroll
            for (int t = 0; t < 8; ++t) {
                const int k = kq + t;
                const int v = (k < N_NODES) ? arow[k] : 0;
                const int m = v > 0;
                afrag[t] = m ? (short)0x3F80 : (short)0;
                msum += m;
            }
        }
        const int g = (k0 >> 3) + quad;          // k-group index into Bpack
        const short8* __restrict__ bg = bbase + (size_t)g * 64 + r16;
        const short8 b0 = bg[0];
        const short8 b1 = bg[16];
        const short8 b2 = bg[32];
        const short8 b3 = bg[48];
        acc[0] = __builtin_amdgcn_mfma_f32_16x16x32_bf16(afrag, b0, acc[0], 0, 0, 0);
        acc[1] = __builtin_amdgcn_mfma_f32_16x16x32_bf16(afrag, b1, acc[1], 0, 0, 0);
        acc[2] = __builtin_amdgcn_mfma_f32_16x16x32_bf16(afrag, b2, acc[2], 0, 0, 0);
        acc[3] = __builtin_amdgcn_mfma_f32_16x16x32_bf16(afrag, b3, acc[3], 0, 0, 0);
        c0v = n0;
        c1v = n1;
    }

    // deg: fold quads (lanes L, L+16, L+32, L+48 share row r16)
    msum += __shfl_down(msum, 32);
    msum += __shfl_down(msum, 16);

    __shared__ float Cred[4][16][64];
    __shared__ int   degred[4][16];
    #pragma unroll
    for (int c = 0; c < 4; ++c) {
        #pragma unroll
        for (int r = 0; r < 4; ++r)
            Cred[wave][quad * 4 + r][c * 16 + r16] = acc[c][r];
    }
    if (lane < 16) degred[wave][lane] = msum;
    __syncthreads();

    for (int e = tidx; e < 16 * 64; e += 256) {
        const int r = e >> 6, n = e & 63;
        const float sum = Cred[0][r][n] + Cred[1][r][n] + Cred[2][r][n] + Cred[3][r][n];
        Cpart[((size_t)q * N_NODES + tile * 16 + r) * 64 + n] = sum;
    }
    if (tidx < 16)
        degpart[q * N_NODES + tile * 16 + tidx] =
            degred[0][tidx] + degred[1][tidx] + degred[2][tidx] + degred[3][tidx];
}

// Kernel 3 (R1 verbatim, runtime S): out[i][n] = (sum_q Cpart[q][i][n]) / deg[i]
__global__ __launch_bounds__(256) void finalize_kernel(
    const float* __restrict__ Cpart, const int* __restrict__ degpart,
    float* __restrict__ out, int S) {
    const int idx = blockIdx.x * 256 + threadIdx.x;
    if (idx >= N_NODES * OUTF) return;
    const int i = idx >> 6;
    float sum = 0.f;
    int deg = 0;
    for (int qq = 0; qq < S; ++qq) {
        sum += Cpart[(size_t)qq * N_NODES * OUTF + idx];
        deg += degpart[qq * N_NODES + i];
    }
    out[idx] = (deg > 0) ? sum / (float)deg : 0.f;
}

extern "C" void kernel_launch(void* const* d_in, const int* in_sizes, int n_in,
                              void* d_out, int out_size, void* d_ws, size_t ws_size,
                              hipStream_t stream) {
    const float* h   = (const float*)d_in[0];
    const int*   adj = (const int*)d_in[1];
    const float* W   = (const float*)d_in[2];
    // d_in[3] (a1) and d_in[4] (a2) are mathematically irrelevant (see header).
    float* out = (float*)d_out;
    char*  ws  = (char*)d_ws;
    const int S = 8;             // runtime value passed to kernels (proven form)

    size_t off = 0;
    unsigned short* Bpack = (unsigned short*)(ws + off);
    off += ((size_t)KPAD * OUTF * 2 + 255) & ~(size_t)255;           // 1.28 MB
    int* degpart = (int*)(ws + off);
    off += ((size_t)S * N_NODES * 4 + 255) & ~(size_t)255;           // 320 KB
    float* Cpart = (float*)(ws + off);                               // 20.48 MB

    wh_pack_kernel<<<dim3(625), dim3(256), 0, stream>>>(h, W, Bpack);
    gat_agg_kernel<<<dim3(625 * S), dim3(256), 0, stream>>>(adj, Bpack, Cpart, degpart, S);
    finalize_kernel<<<dim3((N_NODES * OUTF + 255) / 256), dim3(256), 0, stream>>>(
        Cpart, degpart, out, S);
}